// Round 8
// baseline (363.833 us; speedup 1.0000x reference)
//
#include <hip/hip_runtime.h>

typedef float          f4    __attribute__((ext_vector_type(4)));
typedef unsigned short u16x4 __attribute__((ext_vector_type(4)));

#define EV_G 64            // events per 16-lane group (contiguous, sorted)
#define NG   4             // groups per wave
#define EPW  (EV_G * NG)   // 256 events per wave
#define WPB  4             // waves per block (256 threads)
#define CH   16            // events per chunk (one per sublane)

__device__ __forceinline__ unsigned short f2bf(float f) {
    unsigned u = __float_as_uint(f);
    return (unsigned short)((u + 0x7fffu + ((u >> 16) & 1u)) >> 16);   // RNE
}
__device__ __forceinline__ f4 tofloat(u16x4 u) {
    f4 r;
    r[0] = __uint_as_float((unsigned)u[0] << 16);
    r[1] = __uint_as_float((unsigned)u[1] << 16);
    r[2] = __uint_as_float((unsigned)u[2] << 16);
    r[3] = __uint_as_float((unsigned)u[3] << 16);
    return r;
}

// Fused prep kernel: blocks [0, convBlocks) convert Aval f32 -> bf16 table in
// d_ws; blocks [convBlocks, ...) pre-zero the shared-boundary (atomic) rows.
__global__ __launch_bounds__(256) void prep_kernel(
    const float* __restrict__ A, unsigned short* __restrict__ Abf, long n4,
    const int* __restrict__ acd0, float* __restrict__ out, int ngroups, int M,
    int convBlocks)
{
    if ((int)blockIdx.x < convBlocks) {
        long i = (long)blockIdx.x * 256 + threadIdx.x;
        const long stride = (long)convBlocks * 256;
        for (; i < n4; i += stride) {
            f4 v = __builtin_nontemporal_load(((const f4*)A) + i);
            u16x4 o;
            o[0] = f2bf(v[0]); o[1] = f2bf(v[1]);
            o[2] = f2bf(v[2]); o[3] = f2bf(v[3]);
            ((u16x4*)Abf)[i] = o;   // normal store: table allocates in caches
        }
    } else {
        const int task = ((int)blockIdx.x - convBlocks) * 16 + ((int)threadIdx.x >> 4);
        const int s    = threadIdx.x & 15;
        if (task < 1 || task >= ngroups) return;
        const long m = (long)task * EV_G;
        if (m >= M) return;
        const int t = acd0[m];
        if (acd0[m - 1] != t) return;        // boundary not shared -> no atomics
        f4 z = {0.f, 0.f, 0.f, 0.f};
        __builtin_nontemporal_store(z, (f4*)(out + (size_t)t * 64 + s * 4));
    }
}

__global__ __launch_bounds__(256, 8) void spspmm_seg_kernel(
    const unsigned short* __restrict__ Aval,   // [NNZ_A, 64] bf16 bits
    const float* __restrict__ Bval,   // [NNZ_B]
    const int*   __restrict__ acd0,   // [M] sorted target idx
    const int*   __restrict__ acd1,   // [M] A row idx
    const int*   __restrict__ acd2,   // [M] B idx
    float*       __restrict__ out,    // [TAR, 64]
    int M, int TAR)
{
    const int lane = threadIdx.x & 63;
    const int s    = lane & 15;           // sublane: channels [s*4, s*4+4)
    const int g    = lane >> 4;           // group within wave
    const int wid  = blockIdx.x * WPB + (threadIdx.x >> 6);
    const long gm0 = (long)wid * EPW + (long)g * EV_G;
    if (gm0 >= M) return;
    const long gEnd = (gm0 + EV_G < (long)M) ? gm0 + EV_G : (long)M;
    const int  nev  = (int)(gEnd - gm0);

    const f4 z4 = {0.f, 0.f, 0.f, 0.f};

    const int t_first = acd0[gm0];
    const int t_prev  = (gm0 > 0)   ? acd0[gm0 - 1] : -1;
    const int t_next  = (gEnd < M)  ? acd0[gEnd]    : -1;

    // Leading gap: targets with no events between prev event's target and ours.
    for (int t = t_prev + 1; t < t_first; ++t)
        __builtin_nontemporal_store(z4, (f4*)(out + (size_t)t * 64 + s * 4));

    f4  acc   = z4;
    int cur_t = t_first;

    auto store_acc = [&](bool shared) {
        float* p = out + (size_t)cur_t * 64 + s * 4;
        if (shared) {                      // crosses a group boundary (pre-zeroed)
            atomicAdd(p + 0, acc[0]); atomicAdd(p + 1, acc[1]);
            atomicAdd(p + 2, acc[2]); atomicAdd(p + 3, acc[3]);
        } else {                           // group-exclusive row
            __builtin_nontemporal_store(acc, (f4*)p);
        }
    };
    auto flush = [&](int next_t) {
        store_acc(cur_t == t_first && cur_t == t_prev);
        for (int tz = cur_t + 1; tz < next_t; ++tz)   // interior empty rows
            __builtin_nontemporal_store(z4, (f4*)(out + (size_t)tz * 64 + s * 4));
        acc   = z4;
        cur_t = next_t;
    };

    if (nev == EV_G) {
        #pragma unroll 1
        for (int c = 0; c < EV_G / CH; ++c) {
            const long mb = gm0 + (long)c * CH;
            // Coalesced descriptor load: lane s holds event mb+s of its group.
            const int   t_i = __builtin_nontemporal_load(acd0 + mb + s);
            const int   a_i = __builtin_nontemporal_load(acd1 + mb + s);
            const float b_i = Bval[__builtin_nontemporal_load(acd2 + mb + s)];
            // 16 row gathers batched back-to-back, raw bf16 bits.
            u16x4 v[CH];
            #pragma unroll
            for (int j = 0; j < CH; ++j) {
                const int a = __shfl(a_i, j, 16);
                v[j] = *(const u16x4*)(Aval + (size_t)a * 64 + s * 4);
            }
            // Segment scan (group-uniform control flow).
            #pragma unroll
            for (int j = 0; j < CH; ++j) {
                const int   t  = __shfl(t_i, j, 16);
                const float bv = __shfl(b_i, j, 16);
                if (t != cur_t) flush(t);
                acc += tofloat(v[j]) * bv;
            }
        }
    } else {
        // Tail span (not hit when M % EPW == 0): per-event broadcast loads.
        for (int m = 0; m < nev; ++m) {
            const int   t  = acd0[gm0 + m];
            const int   a  = acd1[gm0 + m];
            const float bv = Bval[acd2[gm0 + m]];
            const u16x4 v  = *(const u16x4*)(Aval + (size_t)a * 64 + s * 4);
            if (t != cur_t) flush(t);
            acc += tofloat(v) * bv;
        }
    }

    // Final segment: shared iff it continues into the next group, or it is the
    // whole-group segment continuing from the previous group.
    store_acc((cur_t == t_next) || (cur_t == t_first && cur_t == t_prev));

    // Trailing gap after the very last event's target.
    if (gEnd == M) {
        const int tl = acd0[M - 1];
        for (int t = tl + 1; t < TAR; ++t)
            __builtin_nontemporal_store(z4, (f4*)(out + (size_t)t * 64 + s * 4));
    }
}

extern "C" void kernel_launch(void* const* d_in, const int* in_sizes, int n_in,
                              void* d_out, int out_size, void* d_ws, size_t ws_size,
                              hipStream_t stream) {
    const float* Aval = (const float*)d_in[0];
    const float* Bval = (const float*)d_in[1];
    const int*   acd0 = (const int*)d_in[2];
    const int*   acd1 = (const int*)d_in[3];
    const int*   acd2 = (const int*)d_in[4];
    float* out = (float*)d_out;
    const int M   = in_sizes[2];
    const int TAR = out_size / 64;
    const long nA_elems = in_sizes[0];          // NNZ_A * 64

    const int ngroups = (M + EV_G - 1) / EV_G;
    unsigned short* Abf = (unsigned short*)d_ws;

    // Fused: bf16 table conversion + pre-zero of atomic-target rows.
    {
        const int convBlocks = 2048;
        const int pzBlocks   = (ngroups + 15) / 16;
        prep_kernel<<<dim3(convBlocks + pzBlocks), dim3(256), 0, stream>>>(
            Aval, Abf, nA_elems / 4, acd0, out, ngroups, M, convBlocks);
    }

    const long nwaves = ((long)M + EPW - 1) / EPW;
    const long blocks = (nwaves + WPB - 1) / WPB;
    spspmm_seg_kernel<<<dim3((unsigned)blocks), dim3(WPB * 64), 0, stream>>>(
        Abf, Bval, acd0, acd1, acd2, out, M, TAR);
}

// Round 9
// 265.549 us; speedup vs baseline: 1.3701x; 1.3701x over previous
//
#include <hip/hip_runtime.h>

typedef float          f4    __attribute__((ext_vector_type(4)));
typedef unsigned short u16x4 __attribute__((ext_vector_type(4)));

#define EV_G 64            // events per 16-lane group (contiguous, sorted)
#define NG   4             // groups per wave
#define EPW  (EV_G * NG)   // 256 events per wave
#define WPB  4             // waves per block (256 threads)
#define CH   32            // events per chunk (two per sublane, 32 gathers in flight)

__device__ __forceinline__ unsigned short f2bf(float f) {
    unsigned u = __float_as_uint(f);
    return (unsigned short)((u + 0x7fffu + ((u >> 16) & 1u)) >> 16);   // RNE
}
__device__ __forceinline__ f4 tofloat(u16x4 u) {
    f4 r;
    r[0] = __uint_as_float((unsigned)u[0] << 16);
    r[1] = __uint_as_float((unsigned)u[1] << 16);
    r[2] = __uint_as_float((unsigned)u[2] << 16);
    r[3] = __uint_as_float((unsigned)u[3] << 16);
    return r;
}

// Fused prep kernel: blocks [0, convBlocks) convert Aval f32 -> bf16 table in
// d_ws; blocks [convBlocks, ...) pre-zero the shared-boundary (atomic) rows.
__global__ __launch_bounds__(256) void prep_kernel(
    const float* __restrict__ A, unsigned short* __restrict__ Abf, long n4,
    const int* __restrict__ acd0, float* __restrict__ out, int ngroups, int M,
    int convBlocks)
{
    if ((int)blockIdx.x < convBlocks) {
        long i = (long)blockIdx.x * 256 + threadIdx.x;
        const long stride = (long)convBlocks * 256;
        for (; i < n4; i += stride) {
            f4 v = __builtin_nontemporal_load(((const f4*)A) + i);
            u16x4 o;
            o[0] = f2bf(v[0]); o[1] = f2bf(v[1]);
            o[2] = f2bf(v[2]); o[3] = f2bf(v[3]);
            ((u16x4*)Abf)[i] = o;   // normal store: table allocates in caches
        }
    } else {
        const int task = ((int)blockIdx.x - convBlocks) * 16 + ((int)threadIdx.x >> 4);
        const int s    = threadIdx.x & 15;
        if (task < 1 || task >= ngroups) return;
        const long m = (long)task * EV_G;
        if (m >= M) return;
        const int t = acd0[m];
        if (acd0[m - 1] != t) return;        // boundary not shared -> no atomics
        f4 z = {0.f, 0.f, 0.f, 0.f};
        __builtin_nontemporal_store(z, (f4*)(out + (size_t)t * 64 + s * 4));
    }
}

__global__ __launch_bounds__(256, 3) void spspmm_seg_kernel(
    const unsigned short* __restrict__ Aval,   // [NNZ_A, 64] bf16 bits
    const float* __restrict__ Bval,   // [NNZ_B]
    const int*   __restrict__ acd0,   // [M] sorted target idx
    const int*   __restrict__ acd1,   // [M] A row idx
    const int*   __restrict__ acd2,   // [M] B idx
    float*       __restrict__ out,    // [TAR, 64]
    int M, int TAR)
{
    const int lane = threadIdx.x & 63;
    const int s    = lane & 15;           // sublane: channels [s*4, s*4+4)
    const int g    = lane >> 4;           // group within wave
    const int wid  = blockIdx.x * WPB + (threadIdx.x >> 6);
    const long gm0 = (long)wid * EPW + (long)g * EV_G;
    if (gm0 >= M) return;
    const long gEnd = (gm0 + EV_G < (long)M) ? gm0 + EV_G : (long)M;
    const int  nev  = (int)(gEnd - gm0);

    const f4 z4 = {0.f, 0.f, 0.f, 0.f};

    const int t_first = acd0[gm0];
    const int t_prev  = (gm0 > 0)   ? acd0[gm0 - 1] : -1;
    const int t_next  = (gEnd < M)  ? acd0[gEnd]    : -1;

    // Leading gap: targets with no events between prev event's target and ours.
    for (int t = t_prev + 1; t < t_first; ++t)
        __builtin_nontemporal_store(z4, (f4*)(out + (size_t)t * 64 + s * 4));

    f4  acc   = z4;
    int cur_t = t_first;

    auto store_acc = [&](bool shared) {
        float* p = out + (size_t)cur_t * 64 + s * 4;
        if (shared) {                      // crosses a group boundary (pre-zeroed)
            atomicAdd(p + 0, acc[0]); atomicAdd(p + 1, acc[1]);
            atomicAdd(p + 2, acc[2]); atomicAdd(p + 3, acc[3]);
        } else {                           // group-exclusive row
            __builtin_nontemporal_store(acc, (f4*)p);
        }
    };
    auto flush = [&](int next_t) {
        store_acc(cur_t == t_first && cur_t == t_prev);
        for (int tz = cur_t + 1; tz < next_t; ++tz)   // interior empty rows
            __builtin_nontemporal_store(z4, (f4*)(out + (size_t)tz * 64 + s * 4));
        acc   = z4;
        cur_t = next_t;
    };

    if (nev == EV_G) {
        #pragma unroll 1
        for (int c = 0; c < EV_G / CH; ++c) {
            const long mb = gm0 + (long)c * CH;
            // Coalesced descriptor loads: lane s holds events mb+s and mb+16+s.
            const int   t0 = __builtin_nontemporal_load(acd0 + mb + s);
            const int   a0 = __builtin_nontemporal_load(acd1 + mb + s);
            const float b0 = Bval[__builtin_nontemporal_load(acd2 + mb + s)];
            const int   t1 = __builtin_nontemporal_load(acd0 + mb + 16 + s);
            const int   a1 = __builtin_nontemporal_load(acd1 + mb + 16 + s);
            const float b1 = Bval[__builtin_nontemporal_load(acd2 + mb + 16 + s)];
            // 32 row gathers batched back-to-back (4 KB in flight per wave).
            u16x4 v[CH];
            #pragma unroll
            for (int j = 0; j < 16; ++j) {
                const int aj0 = __shfl(a0, j, 16);
                const int aj1 = __shfl(a1, j, 16);
                v[j]      = *(const u16x4*)(Aval + (size_t)aj0 * 64 + s * 4);
                v[j + 16] = *(const u16x4*)(Aval + (size_t)aj1 * 64 + s * 4);
            }
            // Segment scan (group-uniform control flow).
            #pragma unroll
            for (int j = 0; j < 16; ++j) {
                const int   t  = __shfl(t0, j, 16);
                const float bv = __shfl(b0, j, 16);
                if (t != cur_t) flush(t);
                acc += tofloat(v[j]) * bv;
            }
            #pragma unroll
            for (int j = 0; j < 16; ++j) {
                const int   t  = __shfl(t1, j, 16);
                const float bv = __shfl(b1, j, 16);
                if (t != cur_t) flush(t);
                acc += tofloat(v[j + 16]) * bv;
            }
        }
    } else {
        // Tail span (not hit when M % EPW == 0): per-event broadcast loads.
        for (int m = 0; m < nev; ++m) {
            const int   t  = acd0[gm0 + m];
            const int   a  = acd1[gm0 + m];
            const float bv = Bval[acd2[gm0 + m]];
            const u16x4 v  = *(const u16x4*)(Aval + (size_t)a * 64 + s * 4);
            if (t != cur_t) flush(t);
            acc += tofloat(v) * bv;
        }
    }

    // Final segment: shared iff it continues into the next group, or it is the
    // whole-group segment continuing from the previous group.
    store_acc((cur_t == t_next) || (cur_t == t_first && cur_t == t_prev));

    // Trailing gap after the very last event's target.
    if (gEnd == M) {
        const int tl = acd0[M - 1];
        for (int t = tl + 1; t < TAR; ++t)
            __builtin_nontemporal_store(z4, (f4*)(out + (size_t)t * 64 + s * 4));
    }
}

extern "C" void kernel_launch(void* const* d_in, const int* in_sizes, int n_in,
                              void* d_out, int out_size, void* d_ws, size_t ws_size,
                              hipStream_t stream) {
    const float* Aval = (const float*)d_in[0];
    const float* Bval = (const float*)d_in[1];
    const int*   acd0 = (const int*)d_in[2];
    const int*   acd1 = (const int*)d_in[3];
    const int*   acd2 = (const int*)d_in[4];
    float* out = (float*)d_out;
    const int M   = in_sizes[2];
    const int TAR = out_size / 64;
    const long nA_elems = in_sizes[0];          // NNZ_A * 64

    const int ngroups = (M + EV_G - 1) / EV_G;
    unsigned short* Abf = (unsigned short*)d_ws;

    // Fused: bf16 table conversion + pre-zero of atomic-target rows.
    {
        const int convBlocks = 2048;
        const int pzBlocks   = (ngroups + 15) / 16;
        prep_kernel<<<dim3(convBlocks + pzBlocks), dim3(256), 0, stream>>>(
            Aval, Abf, nA_elems / 4, acd0, out, ngroups, M, convBlocks);
    }

    const long nwaves = ((long)M + EPW - 1) / EPW;
    const long blocks = (nwaves + WPB - 1) / WPB;
    spspmm_seg_kernel<<<dim3((unsigned)blocks), dim3(WPB * 64), 0, stream>>>(
        Abf, Bval, acd0, acd1, acd2, out, M, TAR);
}